// Round 3
// baseline (1202.027 us; speedup 1.0000x reference)
//
#include <hip/hip_runtime.h>
#include <hip/hip_bf16.h>

// FSNet: embed -> bi-GRU(2) encoder -> broadcast -> bi-GRU(2) decoder
//        -> fc head (64x20) + reconstruction GEMM (64x100x10000)
// External dtypes: float32 everywhere (per reference); x int32. Outputs float32.
// Internal: bf16 only as MFMA operands (converted at staging/preload).

typedef __bf16 bf16x8 __attribute__((ext_vector_type(8)));
typedef float f32x4 __attribute__((ext_vector_type(4)));

__device__ __forceinline__ float bf2f(ushort u) {
    union { unsigned int i; float f; } v; v.i = ((unsigned int)u) << 16; return v.f;
}
__device__ __forceinline__ ushort f2bf(float f) {
    __hip_bfloat16 h = __float2bfloat16(f);   // RNE
    return *reinterpret_cast<ushort*>(&h);
}
// clamp sanitizes NaN -> finite (IEEE v_max_f32 returns the non-NaN operand)
__device__ __forceinline__ float sigm(float x) {
    x = fminf(fmaxf(x, -30.f), 30.f);
    return 1.f / (1.f + __expf(-x));
}
__device__ __forceinline__ float tanh_f(float x) {
    x = fminf(fmaxf(x, -15.f), 15.f);
    float e = __expf(2.f * x);
    return (e - 1.f) / (e + 1.f);
}

// ---------------------------------------------------------------- embedding
// fp32 emb -> bf16 e_buf (A-operand of first GEMM). 8 elements / thread.
__global__ __launch_bounds__(256) void emb_gather(const int* __restrict__ x,
                                                  const float* __restrict__ emb,
                                                  ushort* __restrict__ e) {
    int idx = blockIdx.x * 256 + threadIdx.x;     // < 6400*16
    int row = idx >> 4, k8 = idx & 15;
    int xi = x[row];
    xi = xi > 9999 ? 9999 : (xi < 0 ? 0 : xi);
    const float* src = &emb[(size_t)xi * 128 + k8 * 8];
    ushort4 lo, hi;
    lo.x = f2bf(src[0]); lo.y = f2bf(src[1]); lo.z = f2bf(src[2]); lo.w = f2bf(src[3]);
    hi.x = f2bf(src[4]); hi.y = f2bf(src[5]); hi.z = f2bf(src[6]); hi.w = f2bf(src[7]);
    ushort* dst = &e[row * 128 + k8 * 8];
    *reinterpret_cast<ushort4*>(dst)     = lo;
    *reinterpret_cast<ushort4*>(dst + 4) = hi;
}

// ---------------------------------------------------------------- GEMM C = A @ W.T + bias (fp32 out)
// A: [M][K] bf16 (internal buffer). W: [N][K] fp32 (model weight, bf16-converted in staging).
// 128x128 tile, 4 waves each 64x64, mfma 16x16x32 bf16, K step 64. (m93 pattern)
__global__ __launch_bounds__(256) void gemm_bt(const ushort* __restrict__ A, int lda,
                                               const float* __restrict__ W, int ldw,
                                               const float* __restrict__ bias,
                                               float* __restrict__ C, int ldc,
                                               int M, int N, int K) {
    __shared__ __align__(16) ushort As[128 * 72];   // stride 72: rows 16B-aligned
    __shared__ __align__(16) ushort Ws[128 * 72];
    const int tid = threadIdx.x;
    const int lane = tid & 63, wave = tid >> 6;
    const int n0 = blockIdx.x * 128, m0 = blockIdx.y * 128;
    const int wm = (wave >> 1) * 64, wn = (wave & 1) * 64;
    const int lm = lane & 15, kq = lane >> 4;
    f32x4 acc[4][4] = {};

    for (int kb = 0; kb < K; kb += 64) {
        // A: 128 rows x 64 k of bf16 = 1024 16B-chunks
        #pragma unroll
        for (int it = 0; it < 4; ++it) {
            int chunk = it * 256 + tid;
            int row = chunk >> 3, kc = chunk & 7;
            int gm = m0 + row; gm = gm < M ? gm : M - 1;   // clamp: garbage rows never stored
            *reinterpret_cast<int4*>(&As[row * 72 + kc * 8]) =
                *reinterpret_cast<const int4*>(&A[(size_t)gm * lda + kb + kc * 8]);
        }
        // W: 128 rows x 64 k of fp32 = 2048 float4-chunks; convert to bf16
        #pragma unroll
        for (int it = 0; it < 8; ++it) {
            int chunk = it * 256 + tid;
            int row = chunk >> 4, kc = chunk & 15;
            int gn = n0 + row; gn = gn < N ? gn : N - 1;
            float4 w4 = *reinterpret_cast<const float4*>(&W[(size_t)gn * ldw + kb + kc * 4]);
            ushort4 b4;
            b4.x = f2bf(w4.x); b4.y = f2bf(w4.y); b4.z = f2bf(w4.z); b4.w = f2bf(w4.w);
            *reinterpret_cast<ushort4*>(&Ws[row * 72 + kc * 4]) = b4;
        }
        __syncthreads();
        #pragma unroll
        for (int k2 = 0; k2 < 2; ++k2) {
            bf16x8 af[4], wf[4];
            #pragma unroll
            for (int tt = 0; tt < 4; ++tt) {
                af[tt] = *reinterpret_cast<const bf16x8*>(&As[(wm + tt * 16 + lm) * 72 + k2 * 32 + kq * 8]);
                wf[tt] = *reinterpret_cast<const bf16x8*>(&Ws[(wn + tt * 16 + lm) * 72 + k2 * 32 + kq * 8]);
            }
            #pragma unroll
            for (int tm = 0; tm < 4; ++tm)
                #pragma unroll
                for (int tn = 0; tn < 4; ++tn)
                    acc[tm][tn] = __builtin_amdgcn_mfma_f32_16x16x32_bf16(af[tm], wf[tn], acc[tm][tn], 0, 0, 0);
        }
        __syncthreads();
    }
    float bn[4];
    #pragma unroll
    for (int tn = 0; tn < 4; ++tn) {
        int n = n0 + wn + tn * 16 + lm;
        bn[tn] = (bias != nullptr && n < N) ? bias[n] : 0.f;
    }
    #pragma unroll
    for (int tm = 0; tm < 4; ++tm) {
        int mbase = m0 + wm + tm * 16 + kq * 4;   // C/D: col=lane&15, row=quad*4+reg (m89-verified)
        #pragma unroll
        for (int tn = 0; tn < 4; ++tn) {
            int n = n0 + wn + tn * 16 + lm;
            if (n < N) {
                #pragma unroll
                for (int i = 0; i < 4; ++i) {
                    int m = mbase + i;
                    if (m < M) C[(size_t)m * ldc + n] = acc[tm][tn][i] + bn[tn];
                }
            }
        }
    }
}

// ---------------------------------------------------------------- GRU scan
// grid = 8 blocks: blk = dir*4 + batch_quarter (16 batch rows each). 512 thr (8 waves).
// Per step: gh(16x384) = h(16x128) @ Whh[d].T via MFMA (Whh B-frags preloaded to registers,
// fp32->bf16 once), gh -> LDS transposed (stride 21), then GRU nonlinearity with fp32 h state.
__global__ __launch_bounds__(512) void gru_scan(const float* __restrict__ gi, int gi_tconst,
                                                const float* __restrict__ Whh,   // [2][384][128] fp32
                                                const float* __restrict__ bhh,   // [2][384] fp32
                                                ushort* __restrict__ y,          // [64][100][256] bf16 or null
                                                float* __restrict__ hf32,        // [64][512]
                                                ushort* __restrict__ hbf,        // [64][512] bf16 or null
                                                int hoff) {
    __shared__ __align__(16) ushort hbuf[16 * 136];   // bf16 h copy for MFMA, padded stride
    __shared__ float ghT[384 * 21];                   // ghT[gate_col][batch], stride 21
    const int blk = blockIdx.x;
    const int d = blk >> 2, q = blk & 3;
    const int tid = threadIdx.x;
    const int lane = tid & 63, wave = tid >> 6;
    const int lm = lane & 15, kq = lane >> 4;

    for (int i = tid; i < 16 * 136; i += 512) hbuf[i] = 0;

    // B fragments: B[k][n] = Whh[d][n][k]; wave owns n-tiles wave*3..wave*3+2. Loop-invariant.
    bf16x8 bfr[3][4];
    {
        const float* Wd = Whh + (size_t)d * 384 * 128;
        #pragma unroll
        for (int i = 0; i < 3; ++i) {
            int n = (wave * 3 + i) * 16 + lm;
            #pragma unroll
            for (int kb = 0; kb < 4; ++kb) {
                const float* p = &Wd[(size_t)n * 128 + kb * 32 + kq * 8];
                union { ushort u[8]; bf16x8 v; } t;
                #pragma unroll
                for (int e2 = 0; e2 < 8; ++e2) t.u[e2] = f2bf(p[e2]);
                bfr[i][kb] = t.v;
            }
        }
    }

    const int j = tid & 127;        // hidden index
    const int bg4 = tid >> 7;       // batch group 0..3, each thread owns 4 batch rows
    const float bhr = bhh[d * 384 + j];
    const float bhz = bhh[d * 384 + 128 + j];
    const float bhn = bhh[d * 384 + 256 + j];

    float hreg[4] = {0.f, 0.f, 0.f, 0.f};
    float gcr[4], gcz[4], gcn[4];
    if (gi_tconst) {                 // decoder layer0: gi constant over time
        #pragma unroll
        for (int ii = 0; ii < 4; ++ii) {
            int bgl = q * 16 + bg4 * 4 + ii;
            const float* g = gi + (size_t)bgl * 768 + d * 384;
            gcr[ii] = g[j]; gcz[ii] = g[128 + j]; gcn[ii] = g[256 + j];
        }
    }
    __syncthreads();

    const bool rev = (d == 1);
    for (int ti = 0; ti < 100; ++ti) {
        int t = rev ? 99 - ti : ti;
        float gr[4], gz[4], gn[4];
        if (gi_tconst) {
            #pragma unroll
            for (int ii = 0; ii < 4; ++ii) { gr[ii] = gcr[ii]; gz[ii] = gcz[ii]; gn[ii] = gcn[ii]; }
        } else {
            // issue global gi loads first: latency hides behind MFMA phase
            #pragma unroll
            for (int ii = 0; ii < 4; ++ii) {
                int bgl = q * 16 + bg4 * 4 + ii;
                const float* g = gi + ((size_t)bgl * 100 + t) * 768 + d * 384;
                gr[ii] = g[j]; gz[ii] = g[128 + j]; gn[ii] = g[256 + j];
            }
        }
        // MFMA: gh = h @ Whh.T
        bf16x8 afr[4];
        #pragma unroll
        for (int kb = 0; kb < 4; ++kb)
            afr[kb] = *reinterpret_cast<const bf16x8*>(&hbuf[lm * 136 + kb * 32 + kq * 8]);
        #pragma unroll
        for (int i = 0; i < 3; ++i) {
            f32x4 acc = {0.f, 0.f, 0.f, 0.f};
            #pragma unroll
            for (int kb = 0; kb < 4; ++kb)
                acc = __builtin_amdgcn_mfma_f32_16x16x32_bf16(afr[kb], bfr[i][kb], acc, 0, 0, 0);
            int c = (wave * 3 + i) * 16 + lm;
            float* gp = &ghT[c * 21 + kq * 4];
            gp[0] = acc[0]; gp[1] = acc[1]; gp[2] = acc[2]; gp[3] = acc[3];
        }
        __syncthreads();
        // nonlinearity + state update (fp32 master state in registers)
        #pragma unroll
        for (int ii = 0; ii < 4; ++ii) {
            int bl = bg4 * 4 + ii;
            float ghr = ghT[j * 21 + bl];
            float ghz = ghT[(128 + j) * 21 + bl];
            float ghn = ghT[(256 + j) * 21 + bl];
            float r = sigm(gr[ii] + ghr + bhr);
            float z = sigm(gz[ii] + ghz + bhz);
            float n = tanh_f(gn[ii] + r * (ghn + bhn));
            float h = (1.f - z) * n + z * hreg[ii];
            hreg[ii] = h;
            hbuf[bl * 136 + j] = f2bf(h);
            if (y) {
                int bgl = q * 16 + bl;
                y[((size_t)bgl * 100 + t) * 256 + d * 128 + j] = f2bf(h);
            }
        }
        __syncthreads();
    }
    #pragma unroll
    for (int ii = 0; ii < 4; ++ii) {
        int bgl = q * 16 + bg4 * 4 + ii;
        int col = hoff + d * 128 + j;   // torch hidden layout: [l0f,l0b,l1f,l1b]
        hf32[(size_t)bgl * 512 + col] = hreg[ii];
        if (hbf) hbf[(size_t)bgl * 512 + col] = f2bf(hreg[ii]);
    }
}

// ---------------------------------------------------------------- fc head: out = [enc_h, dec_h] @ fc_W.T + fc_b
__global__ __launch_bounds__(256) void fc_out(const float* __restrict__ ench,
                                              const float* __restrict__ dech,
                                              const float* __restrict__ W,
                                              const float* __restrict__ bias,
                                              float* __restrict__ out) {
    __shared__ float v[1024];
    int b = blockIdx.x, tid = threadIdx.x;
    for (int i = tid; i < 1024; i += 256)
        v[i] = (i < 512) ? ench[b * 512 + i] : dech[b * 512 + i - 512];
    __syncthreads();
    int wave = tid >> 6, lane = tid & 63;
    for (int c = wave; c < 20; c += 4) {
        float s = 0.f;
        for (int k = lane; k < 1024; k += 64) s += v[k] * W[c * 1024 + k];
        #pragma unroll
        for (int off = 32; off >= 1; off >>= 1) s += __shfl_xor(s, off, 64);
        if (lane == 0) out[b * 20 + c] = s + bias[c];
    }
}

// ---------------------------------------------------------------- launch
extern "C" void kernel_launch(void* const* d_in, const int* in_sizes, int n_in,
                              void* d_out, int out_size, void* d_ws, size_t ws_size,
                              hipStream_t stream) {
    const int*   x     = (const int*)  d_in[0];
    const float* emb   = (const float*)d_in[1];
    const float* eWih0 = (const float*)d_in[2];
    const float* eWhh0 = (const float*)d_in[3];
    const float* ebih0 = (const float*)d_in[4];
    const float* ebhh0 = (const float*)d_in[5];
    const float* eWih1 = (const float*)d_in[6];
    const float* eWhh1 = (const float*)d_in[7];
    const float* ebih1 = (const float*)d_in[8];
    const float* ebhh1 = (const float*)d_in[9];
    const float* dWih0 = (const float*)d_in[10];
    const float* dWhh0 = (const float*)d_in[11];
    const float* dbih0 = (const float*)d_in[12];
    const float* dbhh0 = (const float*)d_in[13];
    const float* dWih1 = (const float*)d_in[14];
    const float* dWhh1 = (const float*)d_in[15];
    const float* dbih1 = (const float*)d_in[16];
    const float* dbhh1 = (const float*)d_in[17];
    const float* fcW   = (const float*)d_in[18];
    const float* fcb   = (const float*)d_in[19];
    const float* recW  = (const float*)d_in[20];
    const float* recb  = (const float*)d_in[21];

    char* ws = (char*)d_ws;
    size_t off = 0;
    auto alloc = [&](size_t bytes) {
        char* p = ws + off;
        off = (off + bytes + 255) & ~(size_t)255;
        return p;
    };
    float*  gi    = (float*) alloc((size_t)6400 * 768 * 4);   // per-t gate inputs (fp32, reused 3x)
    ushort* yA    = (ushort*)alloc((size_t)6400 * 256 * 2);   // enc l0 / dec l0 output seq (bf16)
    ushort* y1d   = (ushort*)alloc((size_t)6400 * 256 * 2);   // dec l1 output = rec_seq (bf16)
    ushort* e_buf = (ushort*)alloc((size_t)6400 * 128 * 2);   // gathered embeddings (bf16)
    float*  digi  = (float*) alloc((size_t)64 * 768 * 4);     // dec l0 time-constant gi
    float*  enchf = (float*) alloc((size_t)64 * 512 * 4);
    ushort* enchb = (ushort*)alloc((size_t)64 * 512 * 2);
    float*  dechf = (float*) alloc((size_t)64 * 512 * 4);
    size_t ws_used = off;

    float* out_fc  = (float*)d_out;              // [64][20]
    float* out_rec = (float*)d_out + 1280;       // [64][100][10000]

    hipMemsetAsync(d_ws, 0, ws_used, stream);    // kill any poison-read possibility

    emb_gather<<<6400 * 16 / 256, 256, 0, stream>>>(x, emb, e_buf);
    // encoder layer 0
    gemm_bt<<<dim3(6, 50), 256, 0, stream>>>(e_buf, 128, eWih0, 128, ebih0, gi, 768, 6400, 768, 128);
    gru_scan<<<8, 512, 0, stream>>>(gi, 0, eWhh0, ebhh0, yA, enchf, enchb, 0);
    // encoder layer 1 (y not needed, only final h)
    gemm_bt<<<dim3(6, 50), 256, 0, stream>>>(yA, 256, eWih1, 256, ebih1, gi, 768, 6400, 768, 256);
    gru_scan<<<8, 512, 0, stream>>>(gi, 0, eWhh1, ebhh1, nullptr, enchf, enchb, 256);
    // decoder layer 0: input = broadcast enc_h -> gi constant over t
    gemm_bt<<<dim3(6, 1), 256, 0, stream>>>(enchb, 512, dWih0, 512, dbih0, digi, 768, 64, 768, 512);
    gru_scan<<<8, 512, 0, stream>>>(digi, 1, dWhh0, dbhh0, yA, dechf, nullptr, 0);
    // decoder layer 1
    gemm_bt<<<dim3(6, 50), 256, 0, stream>>>(yA, 256, dWih1, 256, dbih1, gi, 768, 6400, 768, 256);
    gru_scan<<<8, 512, 0, stream>>>(gi, 0, dWhh1, dbhh1, y1d, dechf, nullptr, 256);
    // reconstruction GEMM (dominant): rec = y1d @ rec_W.T + rec_b  (fp32 out, 256 MB)
    gemm_bt<<<dim3(79, 50), 256, 0, stream>>>(y1d, 256, recW, 256, recb, out_rec, 10000, 6400, 10000, 256);
    // fc head
    fc_out<<<64, 256, 0, stream>>>(enchf, dechf, fcW, fcb, out_fc);
}

// Round 4
// 1040.938 us; speedup vs baseline: 1.1548x; 1.1548x over previous
//
#include <hip/hip_runtime.h>
#include <hip/hip_bf16.h>

// FSNet: embed -> bi-GRU(2) encoder -> broadcast -> bi-GRU(2) decoder
//        -> fc head (64x20) + reconstruction GEMM (64x100x10000)
// External dtypes: float32 (per reference); x int32. Outputs float32.
// Internal: bf16 only as MFMA operands.

typedef __bf16 bf16x8 __attribute__((ext_vector_type(8)));
typedef float f32x4 __attribute__((ext_vector_type(4)));

__device__ __forceinline__ ushort f2bf(float f) {
    __hip_bfloat16 h = __float2bfloat16(f);   // RNE
    return *reinterpret_cast<ushort*>(&h);
}
__device__ __forceinline__ float sigm(float x) {          // x finite, |x| small -> no overflow path to NaN
    return 1.f / (1.f + __expf(-x));
}
__device__ __forceinline__ float tanh_f(float x) {
    x = fminf(fmaxf(x, -15.f), 15.f);                     // keeps exp finite; sanitizes NaN
    float e = __expf(2.f * x);
    return (e - 1.f) / (e + 1.f);
}

// ---------------------------------------------------------------- embedding: fp32 emb -> bf16
__global__ __launch_bounds__(256) void emb_gather(const int* __restrict__ x,
                                                  const float* __restrict__ emb,
                                                  ushort* __restrict__ e) {
    int idx = blockIdx.x * 256 + threadIdx.x;     // < 6400*16
    int row = idx >> 4, k8 = idx & 15;
    int xi = x[row];
    xi = xi > 9999 ? 9999 : (xi < 0 ? 0 : xi);
    const float* src = &emb[(size_t)xi * 128 + k8 * 8];
    ushort4 lo, hi;
    lo.x = f2bf(src[0]); lo.y = f2bf(src[1]); lo.z = f2bf(src[2]); lo.w = f2bf(src[3]);
    hi.x = f2bf(src[4]); hi.y = f2bf(src[5]); hi.z = f2bf(src[6]); hi.w = f2bf(src[7]);
    ushort* dst = &e[row * 128 + k8 * 8];
    *reinterpret_cast<ushort4*>(dst)     = lo;
    *reinterpret_cast<ushort4*>(dst + 4) = hi;
}

// ---------------------------------------------------------------- fp32 -> bf16 bulk convert (8/thread)
__global__ __launch_bounds__(256) void cvt_f32_bf16(const float* __restrict__ src,
                                                    ushort* __restrict__ dst, int n8) {
    int i = blockIdx.x * 256 + threadIdx.x;
    if (i >= n8) return;
    const float* s = src + (size_t)i * 8;
    ushort4 lo, hi;
    lo.x = f2bf(s[0]); lo.y = f2bf(s[1]); lo.z = f2bf(s[2]); lo.w = f2bf(s[3]);
    hi.x = f2bf(s[4]); hi.y = f2bf(s[5]); hi.z = f2bf(s[6]); hi.w = f2bf(s[7]);
    ushort* d = dst + (size_t)i * 8;
    *reinterpret_cast<ushort4*>(d)     = lo;
    *reinterpret_cast<ushort4*>(d + 4) = hi;
}

// ---------------------------------------------------------------- GEMM C = A @ W.T + bias (fp32 out)
// A: [M][K] bf16. W: [N][K] fp32 or bf16 (template). 128x128 tile, 4 waves, mfma 16x16x32 bf16.
// bhh_fold (optional, N=768 GRU case): adds bhh[n] for gate cols (n%384)<256 (r,z biases).
template <bool WBF16>
__global__ __launch_bounds__(256) void gemm_bt(const ushort* __restrict__ A, int lda,
                                               const void* __restrict__ Wp, int ldw,
                                               const float* __restrict__ bias,
                                               const float* __restrict__ bhh_fold,
                                               float* __restrict__ C, int ldc,
                                               int M, int N, int K) {
    __shared__ __align__(16) ushort As[128 * 72];   // stride 72: rows 16B-aligned
    __shared__ __align__(16) ushort Ws[128 * 72];
    const int tid = threadIdx.x;
    const int lane = tid & 63, wave = tid >> 6;
    const int n0 = blockIdx.x * 128, m0 = blockIdx.y * 128;
    const int wm = (wave >> 1) * 64, wn = (wave & 1) * 64;
    const int lm = lane & 15, kq = lane >> 4;
    f32x4 acc[4][4] = {};

    for (int kb = 0; kb < K; kb += 64) {
        #pragma unroll
        for (int it = 0; it < 4; ++it) {            // A: 1024 chunks of 16B
            int chunk = it * 256 + tid;
            int row = chunk >> 3, kc = chunk & 7;
            int gm = m0 + row; gm = gm < M ? gm : M - 1;   // clamp: garbage rows never stored
            *reinterpret_cast<int4*>(&As[row * 72 + kc * 8]) =
                *reinterpret_cast<const int4*>(&A[(size_t)gm * lda + kb + kc * 8]);
        }
        if (WBF16) {
            const ushort* W = (const ushort*)Wp;
            #pragma unroll
            for (int it = 0; it < 4; ++it) {
                int chunk = it * 256 + tid;
                int row = chunk >> 3, kc = chunk & 7;
                int gn = n0 + row; gn = gn < N ? gn : N - 1;
                *reinterpret_cast<int4*>(&Ws[row * 72 + kc * 8]) =
                    *reinterpret_cast<const int4*>(&W[(size_t)gn * ldw + kb + kc * 8]);
            }
        } else {
            const float* W = (const float*)Wp;
            #pragma unroll
            for (int it = 0; it < 8; ++it) {        // W fp32: 2048 float4 chunks, cvt to bf16
                int chunk = it * 256 + tid;
                int row = chunk >> 4, kc = chunk & 15;
                int gn = n0 + row; gn = gn < N ? gn : N - 1;
                float4 w4 = *reinterpret_cast<const float4*>(&W[(size_t)gn * ldw + kb + kc * 4]);
                ushort4 b4;
                b4.x = f2bf(w4.x); b4.y = f2bf(w4.y); b4.z = f2bf(w4.z); b4.w = f2bf(w4.w);
                *reinterpret_cast<ushort4*>(&Ws[row * 72 + kc * 4]) = b4;
            }
        }
        __syncthreads();
        #pragma unroll
        for (int k2 = 0; k2 < 2; ++k2) {
            bf16x8 af[4], wf[4];
            #pragma unroll
            for (int tt = 0; tt < 4; ++tt) {
                af[tt] = *reinterpret_cast<const bf16x8*>(&As[(wm + tt * 16 + lm) * 72 + k2 * 32 + kq * 8]);
                wf[tt] = *reinterpret_cast<const bf16x8*>(&Ws[(wn + tt * 16 + lm) * 72 + k2 * 32 + kq * 8]);
            }
            #pragma unroll
            for (int tm = 0; tm < 4; ++tm)
                #pragma unroll
                for (int tn = 0; tn < 4; ++tn)
                    acc[tm][tn] = __builtin_amdgcn_mfma_f32_16x16x32_bf16(af[tm], wf[tn], acc[tm][tn], 0, 0, 0);
        }
        __syncthreads();
    }
    float bn[4];
    #pragma unroll
    for (int tn = 0; tn < 4; ++tn) {
        int n = n0 + wn + tn * 16 + lm;
        float b = 0.f;
        if (n < N) {
            if (bias) b = bias[n];
            if (bhh_fold) {                         // fold bhh for r,z gate columns
                int c = n < 384 ? n : n - 384;
                if (c < 256) b += bhh_fold[n];
            }
        }
        bn[tn] = b;
    }
    #pragma unroll
    for (int tm = 0; tm < 4; ++tm) {
        int mbase = m0 + wm + tm * 16 + kq * 4;   // C/D: col=lane&15, row=quad*4+reg (m89-verified)
        #pragma unroll
        for (int tn = 0; tn < 4; ++tn) {
            int n = n0 + wn + tn * 16 + lm;
            if (n < N) {
                #pragma unroll
                for (int i = 0; i < 4; ++i) {
                    int m = mbase + i;
                    if (m < M) C[(size_t)m * ldc + n] = acc[tm][tn][i] + bn[tn];
                }
            }
        }
    }
}

// ---------------------------------------------------------------- GRU scan (in-register gates)
// 8 blocks = dir*4 + batch_quarter (16 rows). 512 thr = 8 waves.
// Wave w computes n-tiles {w, 8+w, 16+w} => lane (kq,lm) holds ghr/ghz/ghn for
// j = w*16+lm, batch rows kq*4+0..3 IN ACC REGISTERS after MFMA (C/D: col=lane&15,
// row=quad*4+reg). Nonlinearity fully in-register; only h round-trips LDS
// (double-buffered -> ONE barrier/step). gi(t+1) register-prefetched each step.
// bhh r,z biases pre-folded into gi by the GEMM epilogue; only bhn needed here.
__global__ __launch_bounds__(512) void gru_scan(const float* __restrict__ gi, int gi_tconst,
                                                const float* __restrict__ Whh,   // [2][384][128] fp32
                                                const float* __restrict__ bhh,   // [2][384] fp32
                                                ushort* __restrict__ y,          // [64][100][256] bf16 or null
                                                float* __restrict__ hf32,        // [64][512]
                                                ushort* __restrict__ hbf,        // [64][512] bf16 or null
                                                int hoff) {
    __shared__ __align__(16) ushort hbuf[2][16 * 136];   // bf16 h, [b][k] stride 136, double-buffered
    const int d = blockIdx.x >> 2, q = blockIdx.x & 3;
    const int tid = threadIdx.x;
    const int lane = tid & 63, w = tid >> 6;
    const int lm = lane & 15, kq = lane >> 4;
    const int j = w * 16 + lm;                            // this lane's hidden index

    for (int i = tid; i < 16 * 136; i += 512) hbuf[0][i] = 0;

    // B-frags for n-tiles {w, 8+w, 16+w}: lane's col = g*128 + j, k = kb*32 + kq*8 + idx.
    bf16x8 bfr[3][4];
    {
        const float* Wd = Whh + (size_t)d * 384 * 128;
        #pragma unroll
        for (int g = 0; g < 3; ++g)
            #pragma unroll
            for (int kb = 0; kb < 4; ++kb) {
                const float* p = &Wd[(size_t)(g * 128 + j) * 128 + kb * 32 + kq * 8];
                union { ushort u[8]; bf16x8 v; } t;
                #pragma unroll
                for (int e2 = 0; e2 < 8; ++e2) t.u[e2] = f2bf(p[e2]);
                bfr[g][kb] = t.v;
            }
    }
    const float bhn = bhh[d * 384 + 256 + j];
    const bool rev = (d == 1);

    float hreg[4] = {0.f, 0.f, 0.f, 0.f};
    float gr[4], gz[4], gn[4];
    {   // initial gi load (t = first step)
        int t0 = rev ? 99 : 0;
        #pragma unroll
        for (int r = 0; r < 4; ++r) {
            int b = q * 16 + kq * 4 + r;
            const float* g = gi_tconst ? gi + (size_t)b * 768 + d * 384
                                       : gi + ((size_t)b * 100 + t0) * 768 + d * 384;
            gr[r] = g[j]; gz[r] = g[128 + j]; gn[r] = g[256 + j];
        }
    }
    __syncthreads();

    for (int ti = 0; ti < 100; ++ti) {
        int t = rev ? 99 - ti : ti;
        // prefetch gi(t+1): in flight across the whole step's compute
        float pr[4], pz[4], pn[4];
        if (!gi_tconst && ti < 99) {
            int tn2 = rev ? 99 - (ti + 1) : ti + 1;
            #pragma unroll
            for (int r = 0; r < 4; ++r) {
                int b = q * 16 + kq * 4 + r;
                const float* g = gi + ((size_t)b * 100 + tn2) * 768 + d * 384;
                pr[r] = g[j]; pz[r] = g[128 + j]; pn[r] = g[256 + j];
            }
        }
        // A-frags: A[m=lm][k] from current h buffer
        const ushort* hb = hbuf[ti & 1];
        bf16x8 afr[4];
        #pragma unroll
        for (int kb = 0; kb < 4; ++kb)
            afr[kb] = *reinterpret_cast<const bf16x8*>(&hb[lm * 136 + kb * 32 + kq * 8]);
        // gh = h @ Whh.T : three acc chains (r,z,n) land in this lane's registers
        f32x4 aR = {0,0,0,0}, aZ = {0,0,0,0}, aN = {0,0,0,0};
        #pragma unroll
        for (int kb = 0; kb < 4; ++kb) {
            aR = __builtin_amdgcn_mfma_f32_16x16x32_bf16(afr[kb], bfr[0][kb], aR, 0, 0, 0);
            aZ = __builtin_amdgcn_mfma_f32_16x16x32_bf16(afr[kb], bfr[1][kb], aZ, 0, 0, 0);
            aN = __builtin_amdgcn_mfma_f32_16x16x32_bf16(afr[kb], bfr[2][kb], aN, 0, 0, 0);
        }
        // nonlinearity, fully in-register (gi already has bih + bhh_{r,z} folded)
        ushort* hw = hbuf[(ti + 1) & 1];
        #pragma unroll
        for (int r = 0; r < 4; ++r) {
            float rr = sigm(gr[r] + aR[r]);
            float zz = sigm(gz[r] + aZ[r]);
            float nn = tanh_f(gn[r] + rr * (aN[r] + bhn));
            float h = nn + zz * (hreg[r] - nn);
            hreg[r] = h;
            hw[(kq * 4 + r) * 136 + j] = f2bf(h);
            if (y) {
                int b = q * 16 + kq * 4 + r;
                y[((size_t)b * 100 + t) * 256 + d * 128 + j] = f2bf(h);
            }
        }
        if (!gi_tconst && ti < 99) {
            #pragma unroll
            for (int r = 0; r < 4; ++r) { gr[r] = pr[r]; gz[r] = pz[r]; gn[r] = pn[r]; }
        }
        __syncthreads();
    }
    #pragma unroll
    for (int r = 0; r < 4; ++r) {
        int b = q * 16 + kq * 4 + r;
        int col = hoff + d * 128 + j;   // torch hidden layout: [l0f,l0b,l1f,l1b]
        hf32[(size_t)b * 512 + col] = hreg[r];
        if (hbf) hbf[(size_t)b * 512 + col] = f2bf(hreg[r]);
    }
}

// ---------------------------------------------------------------- fc head: out = [enc_h, dec_h] @ fc_W.T + fc_b
__global__ __launch_bounds__(256) void fc_out(const float* __restrict__ ench,
                                              const float* __restrict__ dech,
                                              const float* __restrict__ W,
                                              const float* __restrict__ bias,
                                              float* __restrict__ out) {
    __shared__ float v[1024];
    int b = blockIdx.x, tid = threadIdx.x;
    for (int i = tid; i < 1024; i += 256)
        v[i] = (i < 512) ? ench[b * 512 + i] : dech[b * 512 + i - 512];
    __syncthreads();
    int wave = tid >> 6, lane = tid & 63;
    for (int c = wave; c < 20; c += 4) {
        float s = 0.f;
        for (int k = lane; k < 1024; k += 64) s += v[k] * W[c * 1024 + k];
        #pragma unroll
        for (int off = 32; off >= 1; off >>= 1) s += __shfl_xor(s, off, 64);
        if (lane == 0) out[b * 20 + c] = s + bias[c];
    }
}

// ---------------------------------------------------------------- launch
extern "C" void kernel_launch(void* const* d_in, const int* in_sizes, int n_in,
                              void* d_out, int out_size, void* d_ws, size_t ws_size,
                              hipStream_t stream) {
    const int*   x     = (const int*)  d_in[0];
    const float* emb   = (const float*)d_in[1];
    const float* eWih0 = (const float*)d_in[2];
    const float* eWhh0 = (const float*)d_in[3];
    const float* ebih0 = (const float*)d_in[4];
    const float* ebhh0 = (const float*)d_in[5];
    const float* eWih1 = (const float*)d_in[6];
    const float* eWhh1 = (const float*)d_in[7];
    const float* ebih1 = (const float*)d_in[8];
    const float* ebhh1 = (const float*)d_in[9];
    const float* dWih0 = (const float*)d_in[10];
    const float* dWhh0 = (const float*)d_in[11];
    const float* dbih0 = (const float*)d_in[12];
    const float* dbhh0 = (const float*)d_in[13];
    const float* dWih1 = (const float*)d_in[14];
    const float* dWhh1 = (const float*)d_in[15];
    const float* dbih1 = (const float*)d_in[16];
    const float* dbhh1 = (const float*)d_in[17];
    const float* fcW   = (const float*)d_in[18];
    const float* fcb   = (const float*)d_in[19];
    const float* recW  = (const float*)d_in[20];
    const float* recb  = (const float*)d_in[21];

    char* ws = (char*)d_ws;
    size_t off = 0;
    auto alloc = [&](size_t bytes) {
        char* p = ws + off;
        off = (off + bytes + 255) & ~(size_t)255;
        return p;
    };
    float*  gi    = (float*) alloc((size_t)6400 * 768 * 4);   // gate inputs (fp32, reused 3x)
    ushort* yA    = (ushort*)alloc((size_t)6400 * 256 * 2);   // enc l0 / dec l0 output seq (bf16)
    ushort* y1d   = (ushort*)alloc((size_t)6400 * 256 * 2);   // dec l1 output = rec_seq (bf16)
    ushort* e_buf = (ushort*)alloc((size_t)6400 * 128 * 2);   // embeddings (bf16)
    float*  digi  = (float*) alloc((size_t)64 * 768 * 4);     // dec l0 time-constant gi
    float*  enchf = (float*) alloc((size_t)64 * 512 * 4);
    ushort* enchb = (ushort*)alloc((size_t)64 * 512 * 2);
    float*  dechf = (float*) alloc((size_t)64 * 512 * 4);
    size_t ws_used = off;
    ushort* recWb = (ushort*)gi;   // bf16 recW aliased over gi (gi dead after last scan; 5.12MB <= 19.6MB)

    float* out_fc  = (float*)d_out;              // [64][20]
    float* out_rec = (float*)d_out + 1280;       // [64][100][10000]

    hipMemsetAsync(d_ws, 0, ws_used, stream);

    emb_gather<<<6400 * 16 / 256, 256, 0, stream>>>(x, emb, e_buf);
    // encoder layer 0 (bhh r,z folded into gi)
    gemm_bt<false><<<dim3(6, 50), 256, 0, stream>>>(e_buf, 128, eWih0, 128, ebih0, ebhh0, gi, 768, 6400, 768, 128);
    gru_scan<<<8, 512, 0, stream>>>(gi, 0, eWhh0, ebhh0, yA, enchf, enchb, 0);
    // encoder layer 1 (only final h needed)
    gemm_bt<false><<<dim3(6, 50), 256, 0, stream>>>(yA, 256, eWih1, 256, ebih1, ebhh1, gi, 768, 6400, 768, 256);
    gru_scan<<<8, 512, 0, stream>>>(gi, 0, eWhh1, ebhh1, nullptr, enchf, enchb, 256);
    // decoder layer 0: broadcast enc_h -> gi constant over t
    gemm_bt<false><<<dim3(6, 1), 256, 0, stream>>>(enchb, 512, dWih0, 512, dbih0, dbhh0, digi, 768, 64, 768, 512);
    gru_scan<<<8, 512, 0, stream>>>(digi, 1, dWhh0, dbhh0, yA, dechf, nullptr, 0);
    // decoder layer 1
    gemm_bt<false><<<dim3(6, 50), 256, 0, stream>>>(yA, 256, dWih1, 256, dbih1, dbhh1, gi, 768, 6400, 768, 256);
    gru_scan<<<8, 512, 0, stream>>>(gi, 0, dWhh1, dbhh1, y1d, dechf, nullptr, 256);
    // reconstruction GEMM: pre-convert recW to bf16 (halves the 50x-reread W stream), then GEMM
    cvt_f32_bf16<<<(10000 * 256 / 8 + 255) / 256, 256, 0, stream>>>(recW, recWb, 10000 * 256 / 8);
    gemm_bt<true><<<dim3(79, 50), 256, 0, stream>>>(y1d, 256, recWb, 256, recb, nullptr, out_rec, 10000, 6400, 10000, 256);
    // fc head
    fc_out<<<64, 256, 0, stream>>>(enchf, dechf, fcW, fcb, out_fc);
}